// Round 4
// baseline (653.944 us; speedup 1.0000x reference)
//
#include <hip/hip_runtime.h>
#include <hip/hip_bf16.h>
#include <hip/hip_fp16.h>
#include <math.h>

// ---------------------------------------------------------------------------
// Diffusion renoise-loop + conditional MLP loss, MI355X (gfx950).
// RNG: threefry_partitionable (bit-exact, absmax 0.0 rounds 1-3).
// Argmin: fp16 hi/lo-split MFMA (argmin d2 == argmax (g - dsq/2)), B-panel
// staged through LDS with ping-pong prefetch (round-3 was HBM-latency-bound).
#define BS   128
#define NS   1024
#define HID  512
#define CTX  128
#define TT   100
#define ITERS 8

// ---- workspace layout (bytes) ---------------------------------------------
constexpr size_t OFF_SACP  = 0;         // 100 f32
constexpr size_t OFF_S1M   = 512;       // 100 f32
constexpr size_t OFF_KEYS  = 1024;      // 16 u32
constexpr size_t OFF_CNTG  = 1152;      // 8 u32
constexpr size_t OFF_CNTB  = 1280;      // 8*128 u32 -> 5376
constexpr size_t OFF_LIST  = 8192;      // u16 [2][128][1024] -> 532480
constexpr size_t OFF_BPACK = 532480;    // uint4[128*64*64] = 8 MiB -> 8921088
constexpr size_t OFF_NOISE = 8921088;   // f32 [128*1024*3] -> 10493952
constexpr size_t OFF_NOISY = 10493952;  // f32 [128*1024*3] -> 12066816
constexpr size_t OFF_BIAS  = 12066816;  // f32 [128*512]    -> 12328960
constexpr size_t OFF_PA    = 12328960;  // float4[512]
constexpr size_t OFF_PB    = 12337152;  // float4[512]
constexpr size_t OFF_PC    = 12345344;  // f32[512]
constexpr size_t OFF_PART  = 12347392;  // f32[512] -> 12349440 total ~12.4 MB

typedef __attribute__((ext_vector_type(8))) _Float16 half8;
typedef __attribute__((ext_vector_type(4))) float f32x4;

// ---- threefry2x32-20 -------------------------------------------------------
__device__ __forceinline__ unsigned rotl32(unsigned x, int r) {
  return (x << r) | (x >> (32 - r));
}
__device__ __forceinline__ void tf2x32(unsigned k0, unsigned k1,
                                       unsigned x0, unsigned x1,
                                       unsigned& o0, unsigned& o1) {
  unsigned k2 = k0 ^ k1 ^ 0x1BD11BDAu;
  x0 += k0; x1 += k1;
#define TF_R4(a,b,c,d) \
  x0 += x1; x1 = rotl32(x1,(a)); x1 ^= x0; \
  x0 += x1; x1 = rotl32(x1,(b)); x1 ^= x0; \
  x0 += x1; x1 = rotl32(x1,(c)); x1 ^= x0; \
  x0 += x1; x1 = rotl32(x1,(d)); x1 ^= x0;
  TF_R4(13,15,26,6)   x0 += k1; x1 += k2 + 1u;
  TF_R4(17,29,16,24)  x0 += k2; x1 += k0 + 2u;
  TF_R4(13,15,26,6)   x0 += k0; x1 += k1 + 3u;
  TF_R4(17,29,16,24)  x0 += k1; x1 += k2 + 4u;
  TF_R4(13,15,26,6)   x0 += k2; x1 += k0 + 5u;
#undef TF_R4
  o0 = x0; o1 = x1;
}

__device__ __forceinline__ float bits_to_u(unsigned bits) {
  float f = __uint_as_float((bits >> 9) | 0x3f800000u) - 1.0f;
  float u = f * 2.0f + (-0.99999994f);
  return fmaxf(-0.99999994f, u);
}

__device__ __forceinline__ float nrm_from_idx(unsigned k0, unsigned k1, unsigned idx) {
  unsigned o0, o1;
  tf2x32(k0, k1, 0u, idx, o0, o1);
  return 1.41421356f * erfinvf(bits_to_u(o0 ^ o1));
}

// regenerate the 3 free-dim noise values of point p with iteration key (k0,k1)
__device__ __forceinline__ void regen3(unsigned k0, unsigned k1, int p,
                                       float a, float s,
                                       const float* __restrict__ data,
                                       float* __restrict__ noise_f,
                                       float* __restrict__ noisy_f,
                                       float& y3, float& y4, float& y5) {
  unsigned base = (unsigned)p * 6u;
  float z3 = nrm_from_idx(k0, k1, base + 3u);
  float z4 = nrm_from_idx(k0, k1, base + 4u);
  float z5 = nrm_from_idx(k0, k1, base + 5u);
  noise_f[p*3+0] = z3; noise_f[p*3+1] = z4; noise_f[p*3+2] = z5;
  y3 = __fadd_rn(__fmul_rn(a, data[p*6+3]), __fmul_rn(s, z3));
  y4 = __fadd_rn(__fmul_rn(a, data[p*6+4]), __fmul_rn(s, z4));
  y5 = __fadd_rn(__fmul_rn(a, data[p*6+5]), __fmul_rn(s, z5));
  noisy_f[p*3+0] = y3; noisy_f[p*3+1] = y4; noisy_f[p*3+2] = y5;
}

__device__ __forceinline__ float ftanh(float x) {
  float e = __expf(2.0f * x);
  float r = __builtin_amdgcn_rcpf(e + 1.0f);
  return fmaf(-2.0f, r, 1.0f);
}

// fp16 hi/lo split: x ~= hi + lo with |err| <~ 2^-23 |x|
__device__ __forceinline__ void split16(float x, unsigned short& hi, unsigned short& lo) {
  __half h = __float2half(x);
  float hf = __half2float(h);
  __half l = __float2half(x - hf);
  hi = __half_as_ushort(h);
  lo = __half_as_ushort(l);
}
__device__ __forceinline__ unsigned pack2(unsigned short a, unsigned short b) {
  return (unsigned)a | ((unsigned)b << 16);
}

// ---- kernel 1: tables, iteration keys, counter init ------------------------
__global__ void k_init(float* __restrict__ sacp, float* __restrict__ s1m,
                       unsigned* __restrict__ keys, unsigned* __restrict__ cntg,
                       unsigned* __restrict__ cntb) {
  __shared__ double omb[TT];
  int t = threadIdx.x;
  if (t < TT) {
    const double PI = 3.14159265358979323846;
    double t0 = (double)t / TT, t1 = (double)(t + 1) / TT;
    double c0 = cos((t0 + 0.008) / 1.008 * PI * 0.5); double ab0 = c0 * c0;
    double c1 = cos((t1 + 0.008) / 1.008 * PI * 0.5); double ab1 = c1 * c1;
    double beta = 1.0 - ab1 / ab0;
    if (beta > 0.999) beta = 0.999;
    omb[t] = 1.0 - beta;
  }
  __syncthreads();
  if (t < TT) {
    double acp = 1.0;
    for (int i = 0; i <= t; ++i) acp *= omb[i];
    sacp[t] = (float)sqrt(acp);
    s1m[t]  = (float)sqrt(1.0 - acp);
  }
  if (t >= 128 && t < 128 + ITERS) {
    int k = t - 128;
    unsigned o0, o1;
    tf2x32(0u, 42u, 0u, (unsigned)k, o0, o1);
    keys[2*k] = o0; keys[2*k+1] = o1;
  }
  for (int i = t; i < ITERS; i += blockDim.x) cntg[i] = 0u;
  for (int i = t; i < ITERS * BS; i += blockDim.x) cntb[i] = 0u;
}

// ---- kernel 2: init noise/noisy (free dims) + build Bpack fragments --------
// B-row K-encoding (per candidate c): word w=2d & 2d+1 = pack(hi_d, lo_d)
// for d=0..5; word 12 = pack of split(-dsq/2); words 13..15 = 0.
__global__ __launch_bounds__(256) void k_prep(
    const float* __restrict__ data, const float* __restrict__ noise0,
    const int* __restrict__ ts, const float* __restrict__ sacp,
    const float* __restrict__ s1m,
    uint4* __restrict__ Bpack, float* __restrict__ noise_f,
    float* __restrict__ noisy_f) {
  int p = blockIdx.x * 256 + threadIdx.x;  // 0..131071
  int b = p >> 10, c = p & 1023;
  int t = ts[b];
  float a = sacp[t], s = s1m[t];
  const float* dp = data + (size_t)p * 6;
  float d0 = dp[0], d1 = dp[1], d2 = dp[2], d3 = dp[3], d4 = dp[4], d5 = dp[5];
  float dsq = d0*d0;
  dsq = fmaf(d1, d1, dsq); dsq = fmaf(d2, d2, dsq);
  dsq = fmaf(d3, d3, dsq); dsq = fmaf(d4, d4, dsq); dsq = fmaf(d5, d5, dsq);
  const float* np0 = noise0 + (size_t)p * 6;
  for (int f = 0; f < 3; ++f) {
    float z = np0[3 + f];
    noise_f[p*3 + f] = z;
    noisy_f[p*3 + f] = __fadd_rn(__fmul_rn(a, dp[3 + f]), __fmul_rn(s, z));
  }
  unsigned wds[13];
  float dd[6] = {d0, d1, d2, d3, d4, d5};
#pragma unroll
  for (int d = 0; d < 6; ++d) {
    unsigned short hi, lo; split16(dd[d], hi, lo);
    unsigned pk = pack2(hi, lo);
    wds[2*d] = pk; wds[2*d+1] = pk;
  }
  {
    unsigned short hi, lo; split16(-0.5f * dsq, hi, lo);
    wds[12] = pack2(hi, lo);
  }
  int ct = c >> 4, c15 = c & 15;
  uint4* dst = Bpack + ((size_t)(b * 64 + ct)) * 64;
#pragma unroll
  for (int q = 0; q < 4; ++q) {
    uint4 v;
    v.x = (q*4+0 < 13) ? wds[q*4+0] : 0u;
    v.y = (q*4+1 < 13) ? wds[q*4+1] : 0u;
    v.z = (q*4+2 < 13) ? wds[q*4+2] : 0u;
    v.w = (q*4+3 < 13) ? wds[q*4+3] : 0u;
    dst[q * 16 + c15] = v;
  }
}

// ---- kernel 3: bias = c@Wc + (t/T)*Wt + b1 (blocks 0..255) + weight pack ---
__global__ __launch_bounds__(256) void k_biaspack(
    const float* __restrict__ ctx, const float* __restrict__ Wc,
    const float* __restrict__ Wt, const float* __restrict__ b1,
    const int* __restrict__ ts, float* __restrict__ biasb,
    const float* __restrict__ W1, const float* __restrict__ W2,
    float4* __restrict__ PA, float4* __restrict__ PB, float* __restrict__ PC) {
  if (blockIdx.x == 256) {
    for (int j = threadIdx.x; j < HID; j += 256) {
      PA[j] = make_float4(W1[j], W1[512 + j], W1[1024 + j], W1[1536 + j]);
      PB[j] = make_float4(W1[2048 + j], W1[2560 + j], W2[j*6 + 3], W2[j*6 + 4]);
      PC[j] = W2[j*6 + 5];
    }
    return;
  }
  int idx = blockIdx.x * 256 + threadIdx.x;
  int b = idx >> 9, j = idx & 511;
  const float* c = ctx + (size_t)b * CTX;
  float acc = 0.f;
  for (int q = 0; q < CTX; ++q) acc = fmaf(c[q], Wc[q * HID + j], acc);
  float temb = (float)ts[b] / 100.0f;
  biasb[idx] = acc + temb * Wt[j] + b1[j];
}

// ---- kernel 4: MFMA argmin sweep, LDS-staged B-panel -----------------------
// blockIdx = qb*128 + b (b%8 = XCD affinity). Block: 4 waves x 64 queries
// (4 M-tiles each). B-panel (64 KiB) staged in 4 x 16 KiB chunks, ping-pong:
// global->reg prefetch at chunk top, ds_write + barrier at chunk end.
// C/D layout: col(c)=lane&15, row(q)=(lane>>4)*4+reg; A: m=lane&15, k=quad*8+j.
__global__ __launch_bounds__(256) void k_argmin(
    int k,
    const float* __restrict__ data, const int* __restrict__ ts,
    const float* __restrict__ sacp, const float* __restrict__ s1m,
    const unsigned* __restrict__ keys, unsigned* __restrict__ cntg,
    unsigned* __restrict__ cntb, unsigned short* __restrict__ list,
    const uint4* __restrict__ Bpack, float* __restrict__ noise_f,
    float* __restrict__ noisy_f) {
  int b = blockIdx.x & 127, qb = blockIdx.x >> 7;
  if (k > 0) {
    for (int j = 0; j < k; ++j) if (cntg[j] < 10u) return;  // cont chain
  }
  int cb = (k == 0) ? NS : (int)cntb[(k - 1) * BS + b];
  if (qb * 256 >= cb) return;  // block-uniform early exit (before barriers)
  int tid = (int)threadIdx.x;
  int w = tid >> 6, lane = tid & 63;
  int c15 = lane & 15, quad = lane >> 4;

  __shared__ uint4 stageb[2][1024];        // 2 x 16 KiB B-chunks
  __shared__ unsigned rowbuf[4][64][16];   // A K-rows, per wave 64 queries
  __shared__ int snn[4][64];

  // ---- build phase: each thread builds one query row (A K-encoding) -------
  {
    int i = qb * 256 + tid;
    bool act = (i < cb);
    int n = 0;
    if (act) n = (k == 0) ? i : (int)list[((k - 1) & 1) * BS * NS + b * NS + i];
    snn[tid >> 6][tid & 63] = n;
    float nd[6] = {0.f, 0.f, 0.f, 0.f, 0.f, 0.f};
    if (act) {
      int p = (b << 10) + n;
      nd[0] = data[p*6+0]; nd[1] = data[p*6+1]; nd[2] = data[p*6+2];
      if (k > 0) {
        int t = ts[b];
        regen3(keys[2*(k-1)], keys[2*(k-1)+1], p, sacp[t], s1m[t],
               data, noise_f, noisy_f, nd[3], nd[4], nd[5]);
      } else {
        nd[3] = noisy_f[p*3+0]; nd[4] = noisy_f[p*3+1]; nd[5] = noisy_f[p*3+2];
      }
    }
    unsigned* r = rowbuf[tid >> 6][tid & 63];
#pragma unroll
    for (int d = 0; d < 6; ++d) {
      unsigned short hi, lo; split16(nd[d], hi, lo);
      r[2*d]   = pack2(hi, hi);
      r[2*d+1] = pack2(lo, lo);
    }
    unsigned short oneh = act ? (unsigned short)0x3C00 : (unsigned short)0;
    r[12] = pack2(oneh, oneh);
    r[13] = 0u; r[14] = 0u; r[15] = 0u;
  }
  // ---- stage chunk 0 -------------------------------------------------------
  const uint4* Bsrc = Bpack + (size_t)b * 4096;
  {
    uint4* dst = (uint4*)stageb[0];
#pragma unroll
    for (int j = 0; j < 4; ++j) dst[j * 256 + tid] = Bsrc[j * 256 + tid];
  }
  __syncthreads();

  // ---- load A fragments (4 M-tiles per wave) -------------------------------
  half8 af[4];
#pragma unroll
  for (int t = 0; t < 4; ++t)
    af[t] = __builtin_bit_cast(half8, *(const uint4*)&rowbuf[w][t * 16 + c15][quad * 4]);

  float bv[4][4];
  int   bt[4][4];
#pragma unroll
  for (int t = 0; t < 4; ++t)
#pragma unroll
    for (int r = 0; r < 4; ++r) { bv[t][r] = -__builtin_inff(); bt[t][r] = 0; }

  // ---- main loop: 4 chunks x 16 candidate tiles ----------------------------
  for (int h = 0; h < 4; ++h) {
    uint4 pre[4];
    if (h < 3) {
      const uint4* src = Bsrc + (size_t)(h + 1) * 1024;
#pragma unroll
      for (int j = 0; j < 4; ++j) pre[j] = src[j * 256 + tid];
    }
    const uint4* lbuf = stageb[h & 1];
#pragma unroll 2
    for (int ct = 0; ct < 16; ++ct) {
      half8 bf = __builtin_bit_cast(half8, lbuf[ct * 64 + lane]);
      int ctg = h * 16 + ct;
      f32x4 z = {0.f, 0.f, 0.f, 0.f};
#pragma unroll
      for (int t = 0; t < 4; ++t) {
        f32x4 acc = __builtin_amdgcn_mfma_f32_16x16x32_f16(af[t], bf, z, 0, 0, 0);
#pragma unroll
        for (int r = 0; r < 4; ++r) {
          if (acc[r] > bv[t][r]) { bv[t][r] = acc[r]; bt[t][r] = ctg; }  // first-min
        }
      }
    }
    if (h < 3) {
      uint4* dst = (uint4*)stageb[(h + 1) & 1];
#pragma unroll
      for (int j = 0; j < 4; ++j) dst[j * 256 + tid] = pre[j];
      __syncthreads();
    }
  }

  // ---- cross-col butterfly argmax (ties -> smaller candidate index) --------
  int bc[4][4];
#pragma unroll
  for (int t = 0; t < 4; ++t)
#pragma unroll
    for (int r = 0; r < 4; ++r) bc[t][r] = bt[t][r] * 16 + c15;
#pragma unroll
  for (int m = 1; m < 16; m <<= 1) {
#pragma unroll
    for (int t = 0; t < 4; ++t) {
#pragma unroll
      for (int r = 0; r < 4; ++r) {
        float ov = __shfl_xor(bv[t][r], m);
        int   oc = __shfl_xor(bc[t][r], m);
        bool tk = (ov > bv[t][r]) || (ov == bv[t][r] && oc < bc[t][r]);
        if (tk) { bv[t][r] = ov; bc[t][r] = oc; }
      }
    }
  }
  // ---- writers: lane with c15 == r emits row quad*4 + r of tile t ----------
  int i0w = qb * 256 + w * 64;
  int rr = c15;
#pragma unroll
  for (int t = 0; t < 4; ++t) {
    bool mm = false; int n = 0;
    if (rr < 4) {
      int ql = t * 16 + quad * 4 + rr;
      int i = i0w + ql;
      n = snn[w][ql];
      int bestc = (rr == 0) ? bc[t][0] : (rr == 1) ? bc[t][1]
                : (rr == 2) ? bc[t][2] : bc[t][3];
      mm = (i < cb) && (bestc != n);
    }
    unsigned long long mask = __ballot(mm ? 1 : 0);
    if (mask != 0ull) {
      int leader = __ffsll((unsigned long long)mask) - 1;
      unsigned basev = 0u;
      if (lane == leader) {
        unsigned cw = (unsigned)__popcll(mask);
        basev = atomicAdd(&cntb[k * BS + b], cw);
        atomicAdd(&cntg[k], cw);
      }
      basev = (unsigned)__shfl((int)basev, leader);
      if (mm) {
        int pos = (int)basev + __popcll(mask & ((1ull << lane) - 1ull));
        list[(k & 1) * BS * NS + b * NS + pos] = (unsigned short)n;
      }
    }
  }
}

// ---- kernel 5: apply the final (iteration 7) update ------------------------
__global__ __launch_bounds__(256) void k_fupd(
    const float* __restrict__ data, const int* __restrict__ ts,
    const float* __restrict__ sacp, const float* __restrict__ s1m,
    const unsigned* __restrict__ keys, const unsigned* __restrict__ cntg,
    const unsigned* __restrict__ cntb, const unsigned short* __restrict__ list,
    float* __restrict__ noise_f, float* __restrict__ noisy_f) {
  for (int j = 0; j < ITERS; ++j) if (cntg[j] < 10u) return;  // cont_7
  int b = blockIdx.x >> 2, chunk = blockIdx.x & 3;
  int cb = (int)cntb[7 * BS + b];
  int i = chunk * 256 + (int)threadIdx.x;
  if (i >= cb) return;
  int n = (int)list[1 * BS * NS + b * NS + i];  // iter 7 parity = 1
  int p = (b << 10) + n;
  int t = ts[b];
  float y3, y4, y5;
  regen3(keys[14], keys[15], p, sacp[t], s1m[t], data, noise_f, noisy_f, y3, y4, y5);
}

// ---- kernel 6: conditional MLP + masked SE partial per quarter-batch -------
__global__ __launch_bounds__(256) void k_loss(
    const float* __restrict__ data, const float* __restrict__ noise_f,
    const float* __restrict__ noisy_f, const float* __restrict__ biasb,
    const float4* __restrict__ PA, const float4* __restrict__ PB,
    const float* __restrict__ PC, const float* __restrict__ b2,
    float* __restrict__ part) {
  int b = blockIdx.x >> 2, qq = blockIdx.x & 3;
  int tid = threadIdx.x;
  int p = (b << 10) + qq * 256 + tid;
  float x0 = data[p*6+0], x1 = data[p*6+1], x2 = data[p*6+2];
  float x3 = noisy_f[p*3+0], x4 = noisy_f[p*3+1], x5 = noisy_f[p*3+2];
  float a0 = 0.f, a1 = 0.f, a2 = 0.f;
  const float* bb = biasb + (size_t)b * HID;
#pragma unroll 4
  for (int j = 0; j < HID; ++j) {
    float4 A = PA[j];
    float4 Bv = PB[j];
    float s = x0 * A.x;
    s = fmaf(x1, A.y, s); s = fmaf(x2, A.z, s);
    s = fmaf(x3, A.w, s); s = fmaf(x4, Bv.x, s); s = fmaf(x5, Bv.y, s);
    s += bb[j];
    float h = ftanh(s);
    a0 = fmaf(h, Bv.z, a0);
    a1 = fmaf(h, Bv.w, a1);
    a2 = fmaf(h, PC[j], a2);
  }
  float d0 = (a0 + b2[3]) - noise_f[p*3+0];
  float d1 = (a1 + b2[4]) - noise_f[p*3+1];
  float d2 = (a2 + b2[5]) - noise_f[p*3+2];
  float lsum = d0*d0;
  lsum = fmaf(d1, d1, lsum);
  lsum = fmaf(d2, d2, lsum);
#pragma unroll
  for (int off = 32; off > 0; off >>= 1) lsum += __shfl_down(lsum, off);
  __shared__ float red[4];
  if ((tid & 63) == 0) red[tid >> 6] = lsum;
  __syncthreads();
  if (tid == 0) part[blockIdx.x] = red[0] + red[1] + red[2] + red[3];
}

// ---- kernel 7: final reduce ------------------------------------------------
__global__ void k_red(const float* __restrict__ part, float* __restrict__ out) {
  int b = threadIdx.x;
  if (b < BS) {
    out[b] = (part[4*b] + part[4*b+1] + part[4*b+2] + part[4*b+3]) / 3072.0f;
  }
}

// ---------------------------------------------------------------------------
extern "C" void kernel_launch(void* const* d_in, const int* in_sizes, int n_in,
                              void* d_out, int out_size, void* d_ws, size_t ws_size,
                              hipStream_t stream) {
  (void)in_sizes; (void)n_in; (void)out_size; (void)ws_size;
  const float* data    = (const float*)d_in[0];
  const float* context = (const float*)d_in[1];
  const float* noise0  = (const float*)d_in[2];
  const float* W1      = (const float*)d_in[3];
  const float* Wc      = (const float*)d_in[4];
  const float* Wt      = (const float*)d_in[5];
  const float* b1      = (const float*)d_in[6];
  const float* W2      = (const float*)d_in[7];
  const float* b2      = (const float*)d_in[8];
  const int*   ts      = (const int*)d_in[9];
  float* out = (float*)d_out;

  char* w = (char*)d_ws;
  float*    sacp   = (float*)(w + OFF_SACP);
  float*    s1m    = (float*)(w + OFF_S1M);
  unsigned* keys   = (unsigned*)(w + OFF_KEYS);
  unsigned* cntg   = (unsigned*)(w + OFF_CNTG);
  unsigned* cntb   = (unsigned*)(w + OFF_CNTB);
  unsigned short* list = (unsigned short*)(w + OFF_LIST);
  uint4*    Bpack  = (uint4*)(w + OFF_BPACK);
  float*    noisef = (float*)(w + OFF_NOISE);
  float*    noisyf = (float*)(w + OFF_NOISY);
  float*    biasb  = (float*)(w + OFF_BIAS);
  float4*   PA     = (float4*)(w + OFF_PA);
  float4*   PB     = (float4*)(w + OFF_PB);
  float*    PC     = (float*)(w + OFF_PC);
  float*    part   = (float*)(w + OFF_PART);

  k_init<<<1, 256, 0, stream>>>(sacp, s1m, keys, cntg, cntb);
  k_biaspack<<<257, 256, 0, stream>>>(context, Wc, Wt, b1, ts, biasb,
                                      W1, W2, PA, PB, PC);
  k_prep<<<512, 256, 0, stream>>>(data, noise0, ts, sacp, s1m, Bpack, noisef, noisyf);
  for (int k = 0; k < ITERS; ++k) {
    k_argmin<<<512, 256, 0, stream>>>(k, data, ts, sacp, s1m, keys, cntg, cntb,
                                      list, Bpack, noisef, noisyf);
  }
  k_fupd<<<512, 256, 0, stream>>>(data, ts, sacp, s1m, keys, cntg, cntb, list,
                                  noisef, noisyf);
  k_loss<<<512, 256, 0, stream>>>(data, noisef, noisyf, biasb, PA, PB, PC, b2, part);
  k_red<<<1, 128, 0, stream>>>(part, out);
}

// Round 5
// 388.064 us; speedup vs baseline: 1.6851x; 1.6851x over previous
//
#include <hip/hip_runtime.h>
#include <hip/hip_bf16.h>
#include <hip/hip_fp16.h>
#include <math.h>

// ---------------------------------------------------------------------------
// Diffusion renoise-loop + conditional MLP loss, MI355X (gfx950).
// RNG: threefry_partitionable (bit-exact, absmax 0.0 rounds 1-4).
// Argmin: fp16 hi/lo-split MFMA (argmin d2 == argmax (g - dsq/2)), LDS-staged
// B-panel. Round-5 fix: same-address device atomics were the ~105us stall
// (8192 serialized adds to cntg[k]); now 64 padded slots + 1 atomic/wave.
#define BS   128
#define NS   1024
#define HID  512
#define CTX  128
#define TT   100
#define ITERS 8

// ---- workspace layout (bytes) ---------------------------------------------
constexpr size_t OFF_SACP  = 0;         // 100 f32
constexpr size_t OFF_S1M   = 512;       // 100 f32
constexpr size_t OFF_KEYS  = 1024;      // 16 u32
constexpr size_t OFF_CNTG  = 1152;      // u32[8][64] padded slots -> 3200
constexpr size_t OFF_CNTB  = 3200;      // u32[8][128] -> 7296
constexpr size_t OFF_LIST  = 8192;      // u16 [2][128][1024] -> 532480
constexpr size_t OFF_BPACK = 532480;    // uint4[128*64*64] = 8 MiB -> 8921088
constexpr size_t OFF_NOISE = 8921088;   // f32 [128*1024*3] -> 10493952
constexpr size_t OFF_NOISY = 10493952;  // f32 [128*1024*3] -> 12066816
constexpr size_t OFF_BIAS  = 12066816;  // f32 [128*512]    -> 12328960
constexpr size_t OFF_PA    = 12328960;  // float4[512]
constexpr size_t OFF_PB    = 12337152;  // float4[512]
constexpr size_t OFF_PC    = 12345344;  // f32[512]
constexpr size_t OFF_PART  = 12347392;  // f32[512] -> 12349440 total ~12.4 MB

typedef __attribute__((ext_vector_type(8))) _Float16 half8;
typedef __attribute__((ext_vector_type(4))) float f32x4;

// ---- threefry2x32-20 -------------------------------------------------------
__device__ __forceinline__ unsigned rotl32(unsigned x, int r) {
  return (x << r) | (x >> (32 - r));
}
__device__ __forceinline__ void tf2x32(unsigned k0, unsigned k1,
                                       unsigned x0, unsigned x1,
                                       unsigned& o0, unsigned& o1) {
  unsigned k2 = k0 ^ k1 ^ 0x1BD11BDAu;
  x0 += k0; x1 += k1;
#define TF_R4(a,b,c,d) \
  x0 += x1; x1 = rotl32(x1,(a)); x1 ^= x0; \
  x0 += x1; x1 = rotl32(x1,(b)); x1 ^= x0; \
  x0 += x1; x1 = rotl32(x1,(c)); x1 ^= x0; \
  x0 += x1; x1 = rotl32(x1,(d)); x1 ^= x0;
  TF_R4(13,15,26,6)   x0 += k1; x1 += k2 + 1u;
  TF_R4(17,29,16,24)  x0 += k2; x1 += k0 + 2u;
  TF_R4(13,15,26,6)   x0 += k0; x1 += k1 + 3u;
  TF_R4(17,29,16,24)  x0 += k1; x1 += k2 + 4u;
  TF_R4(13,15,26,6)   x0 += k2; x1 += k0 + 5u;
#undef TF_R4
  o0 = x0; o1 = x1;
}

__device__ __forceinline__ float bits_to_u(unsigned bits) {
  float f = __uint_as_float((bits >> 9) | 0x3f800000u) - 1.0f;
  float u = f * 2.0f + (-0.99999994f);
  return fmaxf(-0.99999994f, u);
}

__device__ __forceinline__ float nrm_from_idx(unsigned k0, unsigned k1, unsigned idx) {
  unsigned o0, o1;
  tf2x32(k0, k1, 0u, idx, o0, o1);
  return 1.41421356f * erfinvf(bits_to_u(o0 ^ o1));
}

// regenerate the 3 free-dim noise values of point p with iteration key (k0,k1)
__device__ __forceinline__ void regen3(unsigned k0, unsigned k1, int p,
                                       float a, float s,
                                       const float* __restrict__ data,
                                       float* __restrict__ noise_f,
                                       float* __restrict__ noisy_f,
                                       float& y3, float& y4, float& y5) {
  unsigned base = (unsigned)p * 6u;
  float z3 = nrm_from_idx(k0, k1, base + 3u);
  float z4 = nrm_from_idx(k0, k1, base + 4u);
  float z5 = nrm_from_idx(k0, k1, base + 5u);
  noise_f[p*3+0] = z3; noise_f[p*3+1] = z4; noise_f[p*3+2] = z5;
  y3 = __fadd_rn(__fmul_rn(a, data[p*6+3]), __fmul_rn(s, z3));
  y4 = __fadd_rn(__fmul_rn(a, data[p*6+4]), __fmul_rn(s, z4));
  y5 = __fadd_rn(__fmul_rn(a, data[p*6+5]), __fmul_rn(s, z5));
  noisy_f[p*3+0] = y3; noisy_f[p*3+1] = y4; noisy_f[p*3+2] = y5;
}

__device__ __forceinline__ float ftanh(float x) {
  float e = __expf(2.0f * x);
  float r = __builtin_amdgcn_rcpf(e + 1.0f);
  return fmaf(-2.0f, r, 1.0f);
}

// fp16 hi/lo split: x ~= hi + lo with |err| <~ 2^-23 |x|
__device__ __forceinline__ void split16(float x, unsigned short& hi, unsigned short& lo) {
  __half h = __float2half(x);
  float hf = __half2float(h);
  __half l = __float2half(x - hf);
  hi = __half_as_ushort(h);
  lo = __half_as_ushort(l);
}
__device__ __forceinline__ unsigned pack2(unsigned short a, unsigned short b) {
  return (unsigned)a | ((unsigned)b << 16);
}

// cont check: for every j < k, sum of the 64 cntg slots must be >= 10.
// Per-wave, no barrier: lane l loads slot l, 6-step butterfly sum.
__device__ __forceinline__ bool cont_ok(const unsigned* __restrict__ cntg,
                                        int k, int lane) {
  for (int j = 0; j < k; ++j) {
    unsigned v = cntg[j * 64 + lane];
#pragma unroll
    for (int m = 32; m >= 1; m >>= 1) v += (unsigned)__shfl_xor((int)v, m);
    if (v < 10u) return false;
  }
  return true;
}

// ---- kernel 1: tables, iteration keys, counter init ------------------------
__global__ void k_init(float* __restrict__ sacp, float* __restrict__ s1m,
                       unsigned* __restrict__ keys, unsigned* __restrict__ cntg,
                       unsigned* __restrict__ cntb) {
  __shared__ double omb[TT];
  int t = threadIdx.x;
  if (t < TT) {
    const double PI = 3.14159265358979323846;
    double t0 = (double)t / TT, t1 = (double)(t + 1) / TT;
    double c0 = cos((t0 + 0.008) / 1.008 * PI * 0.5); double ab0 = c0 * c0;
    double c1 = cos((t1 + 0.008) / 1.008 * PI * 0.5); double ab1 = c1 * c1;
    double beta = 1.0 - ab1 / ab0;
    if (beta > 0.999) beta = 0.999;
    omb[t] = 1.0 - beta;
  }
  __syncthreads();
  if (t < TT) {
    double acp = 1.0;
    for (int i = 0; i <= t; ++i) acp *= omb[i];
    sacp[t] = (float)sqrt(acp);
    s1m[t]  = (float)sqrt(1.0 - acp);
  }
  if (t >= 128 && t < 128 + ITERS) {
    int k = t - 128;
    unsigned o0, o1;
    tf2x32(0u, 42u, 0u, (unsigned)k, o0, o1);
    keys[2*k] = o0; keys[2*k+1] = o1;
  }
  for (int i = t; i < ITERS * 64; i += blockDim.x) cntg[i] = 0u;
  for (int i = t; i < ITERS * BS; i += blockDim.x) cntb[i] = 0u;
}

// ---- kernel 2: init noise/noisy (free dims) + build Bpack fragments --------
__global__ __launch_bounds__(256) void k_prep(
    const float* __restrict__ data, const float* __restrict__ noise0,
    const int* __restrict__ ts, const float* __restrict__ sacp,
    const float* __restrict__ s1m,
    uint4* __restrict__ Bpack, float* __restrict__ noise_f,
    float* __restrict__ noisy_f) {
  int p = blockIdx.x * 256 + threadIdx.x;  // 0..131071
  int b = p >> 10, c = p & 1023;
  int t = ts[b];
  float a = sacp[t], s = s1m[t];
  const float* dp = data + (size_t)p * 6;
  float d0 = dp[0], d1 = dp[1], d2 = dp[2], d3 = dp[3], d4 = dp[4], d5 = dp[5];
  float dsq = d0*d0;
  dsq = fmaf(d1, d1, dsq); dsq = fmaf(d2, d2, dsq);
  dsq = fmaf(d3, d3, dsq); dsq = fmaf(d4, d4, dsq); dsq = fmaf(d5, d5, dsq);
  const float* np0 = noise0 + (size_t)p * 6;
  for (int f = 0; f < 3; ++f) {
    float z = np0[3 + f];
    noise_f[p*3 + f] = z;
    noisy_f[p*3 + f] = __fadd_rn(__fmul_rn(a, dp[3 + f]), __fmul_rn(s, z));
  }
  unsigned wds[13];
  float dd[6] = {d0, d1, d2, d3, d4, d5};
#pragma unroll
  for (int d = 0; d < 6; ++d) {
    unsigned short hi, lo; split16(dd[d], hi, lo);
    unsigned pk = pack2(hi, lo);
    wds[2*d] = pk; wds[2*d+1] = pk;
  }
  {
    unsigned short hi, lo; split16(-0.5f * dsq, hi, lo);
    wds[12] = pack2(hi, lo);
  }
  int ct = c >> 4, c15 = c & 15;
  uint4* dst = Bpack + ((size_t)(b * 64 + ct)) * 64;
#pragma unroll
  for (int q = 0; q < 4; ++q) {
    uint4 v;
    v.x = (q*4+0 < 13) ? wds[q*4+0] : 0u;
    v.y = (q*4+1 < 13) ? wds[q*4+1] : 0u;
    v.z = (q*4+2 < 13) ? wds[q*4+2] : 0u;
    v.w = (q*4+3 < 13) ? wds[q*4+3] : 0u;
    dst[q * 16 + c15] = v;
  }
}

// ---- kernel 3: bias = c@Wc + (t/T)*Wt + b1 (blocks 0..255) + weight pack ---
__global__ __launch_bounds__(256) void k_biaspack(
    const float* __restrict__ ctx, const float* __restrict__ Wc,
    const float* __restrict__ Wt, const float* __restrict__ b1,
    const int* __restrict__ ts, float* __restrict__ biasb,
    const float* __restrict__ W1, const float* __restrict__ W2,
    float4* __restrict__ PA, float4* __restrict__ PB, float* __restrict__ PC) {
  if (blockIdx.x == 256) {
    for (int j = threadIdx.x; j < HID; j += 256) {
      PA[j] = make_float4(W1[j], W1[512 + j], W1[1024 + j], W1[1536 + j]);
      PB[j] = make_float4(W1[2048 + j], W1[2560 + j], W2[j*6 + 3], W2[j*6 + 4]);
      PC[j] = W2[j*6 + 5];
    }
    return;
  }
  int idx = blockIdx.x * 256 + threadIdx.x;
  int b = idx >> 9, j = idx & 511;
  const float* c = ctx + (size_t)b * CTX;
  float acc = 0.f;
  for (int q = 0; q < CTX; ++q) acc = fmaf(c[q], Wc[q * HID + j], acc);
  float temb = (float)ts[b] / 100.0f;
  biasb[idx] = acc + temb * Wt[j] + b1[j];
}

// ---- kernel 4: MFMA argmin sweep, LDS-staged B-panel -----------------------
// blockIdx = qb*128 + b. Block: 4 waves x 64 queries (4 M-tiles each).
// B-panel 64 KiB staged in 4 x 16 KiB ping-pong chunks.
// C/D layout: col(c)=lane&15, row(q)=(lane>>4)*4+reg; A: m=lane&15, k=quad*8+j.
// Atomics: ONE per wave (total of 4 ballots) to cntb + padded cntg slot.
__global__ __launch_bounds__(256) void k_argmin(
    int k,
    const float* __restrict__ data, const int* __restrict__ ts,
    const float* __restrict__ sacp, const float* __restrict__ s1m,
    const unsigned* __restrict__ keys, unsigned* __restrict__ cntg,
    unsigned* __restrict__ cntb, unsigned short* __restrict__ list,
    const uint4* __restrict__ Bpack, float* __restrict__ noise_f,
    float* __restrict__ noisy_f) {
  int b = blockIdx.x & 127, qb = blockIdx.x >> 7;
  int tid = (int)threadIdx.x;
  int w = tid >> 6, lane = tid & 63;
  int c15 = lane & 15, quad = lane >> 4;
  if (k > 0) {
    if (!cont_ok(cntg, k, lane)) return;  // block-uniform verdict
  }
  int cb = (k == 0) ? NS : (int)cntb[(k - 1) * BS + b];
  if (qb * 256 >= cb) return;  // block-uniform early exit (before barriers)

  __shared__ uint4 stageb[2][1024];        // 2 x 16 KiB B-chunks
  __shared__ unsigned rowbuf[4][64][16];   // A K-rows, per wave 64 queries
  __shared__ int snn[4][64];

  // ---- build phase: each thread builds one query row (A K-encoding) -------
  {
    int i = qb * 256 + tid;
    bool act = (i < cb);
    int n = 0;
    if (act) n = (k == 0) ? i : (int)list[((k - 1) & 1) * BS * NS + b * NS + i];
    snn[w][lane] = n;
    float nd[6] = {0.f, 0.f, 0.f, 0.f, 0.f, 0.f};
    if (act) {
      int p = (b << 10) + n;
      nd[0] = data[p*6+0]; nd[1] = data[p*6+1]; nd[2] = data[p*6+2];
      if (k > 0) {
        int t = ts[b];
        regen3(keys[2*(k-1)], keys[2*(k-1)+1], p, sacp[t], s1m[t],
               data, noise_f, noisy_f, nd[3], nd[4], nd[5]);
      } else {
        nd[3] = noisy_f[p*3+0]; nd[4] = noisy_f[p*3+1]; nd[5] = noisy_f[p*3+2];
      }
    }
    unsigned* r = rowbuf[w][lane];
#pragma unroll
    for (int d = 0; d < 6; ++d) {
      unsigned short hi, lo; split16(nd[d], hi, lo);
      r[2*d]   = pack2(hi, hi);
      r[2*d+1] = pack2(lo, lo);
    }
    unsigned short oneh = act ? (unsigned short)0x3C00 : (unsigned short)0;
    r[12] = pack2(oneh, oneh);
    r[13] = 0u; r[14] = 0u; r[15] = 0u;
  }
  // ---- stage chunk 0 -------------------------------------------------------
  const uint4* Bsrc = Bpack + (size_t)b * 4096;
  {
    uint4* dst = (uint4*)stageb[0];
#pragma unroll
    for (int j = 0; j < 4; ++j) dst[j * 256 + tid] = Bsrc[j * 256 + tid];
  }
  __syncthreads();

  // ---- load A fragments (4 M-tiles per wave) -------------------------------
  half8 af[4];
#pragma unroll
  for (int t = 0; t < 4; ++t)
    af[t] = __builtin_bit_cast(half8, *(const uint4*)&rowbuf[w][t * 16 + c15][quad * 4]);

  float bv[4][4];
  int   bt[4][4];
#pragma unroll
  for (int t = 0; t < 4; ++t)
#pragma unroll
    for (int r = 0; r < 4; ++r) { bv[t][r] = -__builtin_inff(); bt[t][r] = 0; }

  // ---- main loop: 4 chunks x 16 candidate tiles ----------------------------
  for (int h = 0; h < 4; ++h) {
    uint4 pre[4];
    if (h < 3) {
      const uint4* src = Bsrc + (size_t)(h + 1) * 1024;
#pragma unroll
      for (int j = 0; j < 4; ++j) pre[j] = src[j * 256 + tid];
    }
    const uint4* lbuf = stageb[h & 1];
#pragma unroll 2
    for (int ct = 0; ct < 16; ++ct) {
      half8 bf = __builtin_bit_cast(half8, lbuf[ct * 64 + lane]);
      int ctg = h * 16 + ct;
      f32x4 z = {0.f, 0.f, 0.f, 0.f};
#pragma unroll
      for (int t = 0; t < 4; ++t) {
        f32x4 acc = __builtin_amdgcn_mfma_f32_16x16x32_f16(af[t], bf, z, 0, 0, 0);
#pragma unroll
        for (int r = 0; r < 4; ++r) {
          if (acc[r] > bv[t][r]) { bv[t][r] = acc[r]; bt[t][r] = ctg; }  // first-min
        }
      }
    }
    if (h < 3) {
      uint4* dst = (uint4*)stageb[(h + 1) & 1];
#pragma unroll
      for (int j = 0; j < 4; ++j) dst[j * 256 + tid] = pre[j];
      __syncthreads();
    }
  }

  // ---- cross-col butterfly argmax (ties -> smaller candidate index) --------
  int bc[4][4];
#pragma unroll
  for (int t = 0; t < 4; ++t)
#pragma unroll
    for (int r = 0; r < 4; ++r) bc[t][r] = bt[t][r] * 16 + c15;
#pragma unroll
  for (int m = 1; m < 16; m <<= 1) {
#pragma unroll
    for (int t = 0; t < 4; ++t) {
#pragma unroll
      for (int r = 0; r < 4; ++r) {
        float ov = __shfl_xor(bv[t][r], m);
        int   oc = __shfl_xor(bc[t][r], m);
        bool tk = (ov > bv[t][r]) || (ov == bv[t][r] && oc < bc[t][r]);
        if (tk) { bv[t][r] = ov; bc[t][r] = oc; }
      }
    }
  }
  // ---- writers: 4 ballots gathered, ONE atomic pair per wave ---------------
  int i0w = qb * 256 + w * 64;
  int rr = c15;
  unsigned long long masks[4];
  unsigned cw4[4];
  bool mmv[4]; int nv[4];
  unsigned tot = 0u;
#pragma unroll
  for (int t = 0; t < 4; ++t) {
    bool mm = false; int n = 0;
    if (rr < 4) {
      int ql = t * 16 + quad * 4 + rr;
      int i = i0w + ql;
      n = snn[w][ql];
      int bestc = (rr == 0) ? bc[t][0] : (rr == 1) ? bc[t][1]
                : (rr == 2) ? bc[t][2] : bc[t][3];
      mm = (i < cb) && (bestc != n);
    }
    masks[t] = __ballot(mm ? 1 : 0);
    cw4[t] = (unsigned)__popcll(masks[t]);
    mmv[t] = mm; nv[t] = n;
    tot += cw4[t];
  }
  if (tot != 0u) {  // wave-uniform
    unsigned basev = 0u;
    if (lane == 0) {
      basev = atomicAdd(&cntb[k * BS + b], tot);
      atomicAdd(&cntg[k * 64 + ((int)blockIdx.x & 63)], tot);
    }
    basev = (unsigned)__shfl((int)basev, 0);
    unsigned pref = 0u;
#pragma unroll
    for (int t = 0; t < 4; ++t) {
      if (mmv[t]) {
        int pos = (int)(basev + pref) + __popcll(masks[t] & ((1ull << lane) - 1ull));
        list[(k & 1) * BS * NS + b * NS + pos] = (unsigned short)nv[t];
      }
      pref += cw4[t];
    }
  }
}

// ---- kernel 5: apply the final (iteration 7) update ------------------------
__global__ __launch_bounds__(256) void k_fupd(
    const float* __restrict__ data, const int* __restrict__ ts,
    const float* __restrict__ sacp, const float* __restrict__ s1m,
    const unsigned* __restrict__ keys, const unsigned* __restrict__ cntg,
    const unsigned* __restrict__ cntb, const unsigned short* __restrict__ list,
    float* __restrict__ noise_f, float* __restrict__ noisy_f) {
  int lane = (int)threadIdx.x & 63;
  if (!cont_ok(cntg, ITERS, lane)) return;  // cont_7
  int b = blockIdx.x >> 2, chunk = blockIdx.x & 3;
  int cb = (int)cntb[7 * BS + b];
  int i = chunk * 256 + (int)threadIdx.x;
  if (i >= cb) return;
  int n = (int)list[1 * BS * NS + b * NS + i];  // iter 7 parity = 1
  int p = (b << 10) + n;
  int t = ts[b];
  float y3, y4, y5;
  regen3(keys[14], keys[15], p, sacp[t], s1m[t], data, noise_f, noisy_f, y3, y4, y5);
}

// ---- kernel 6: conditional MLP + masked SE partial per quarter-batch -------
__global__ __launch_bounds__(256) void k_loss(
    const float* __restrict__ data, const float* __restrict__ noise_f,
    const float* __restrict__ noisy_f, const float* __restrict__ biasb,
    const float4* __restrict__ PA, const float4* __restrict__ PB,
    const float* __restrict__ PC, const float* __restrict__ b2,
    float* __restrict__ part) {
  int b = blockIdx.x >> 2, qq = blockIdx.x & 3;
  int tid = threadIdx.x;
  int p = (b << 10) + qq * 256 + tid;
  float x0 = data[p*6+0], x1 = data[p*6+1], x2 = data[p*6+2];
  float x3 = noisy_f[p*3+0], x4 = noisy_f[p*3+1], x5 = noisy_f[p*3+2];
  float a0 = 0.f, a1 = 0.f, a2 = 0.f;
  const float* bb = biasb + (size_t)b * HID;
#pragma unroll 4
  for (int j = 0; j < HID; ++j) {
    float4 A = PA[j];
    float4 Bv = PB[j];
    float s = x0 * A.x;
    s = fmaf(x1, A.y, s); s = fmaf(x2, A.z, s);
    s = fmaf(x3, A.w, s); s = fmaf(x4, Bv.x, s); s = fmaf(x5, Bv.y, s);
    s += bb[j];
    float h = ftanh(s);
    a0 = fmaf(h, Bv.z, a0);
    a1 = fmaf(h, Bv.w, a1);
    a2 = fmaf(h, PC[j], a2);
  }
  float d0 = (a0 + b2[3]) - noise_f[p*3+0];
  float d1 = (a1 + b2[4]) - noise_f[p*3+1];
  float d2 = (a2 + b2[5]) - noise_f[p*3+2];
  float lsum = d0*d0;
  lsum = fmaf(d1, d1, lsum);
  lsum = fmaf(d2, d2, lsum);
#pragma unroll
  for (int off = 32; off > 0; off >>= 1) lsum += __shfl_down(lsum, off);
  __shared__ float red[4];
  if ((tid & 63) == 0) red[tid >> 6] = lsum;
  __syncthreads();
  if (tid == 0) part[blockIdx.x] = red[0] + red[1] + red[2] + red[3];
}

// ---- kernel 7: final reduce ------------------------------------------------
__global__ void k_red(const float* __restrict__ part, float* __restrict__ out) {
  int b = threadIdx.x;
  if (b < BS) {
    out[b] = (part[4*b] + part[4*b+1] + part[4*b+2] + part[4*b+3]) / 3072.0f;
  }
}

// ---------------------------------------------------------------------------
extern "C" void kernel_launch(void* const* d_in, const int* in_sizes, int n_in,
                              void* d_out, int out_size, void* d_ws, size_t ws_size,
                              hipStream_t stream) {
  (void)in_sizes; (void)n_in; (void)out_size; (void)ws_size;
  const float* data    = (const float*)d_in[0];
  const float* context = (const float*)d_in[1];
  const float* noise0  = (const float*)d_in[2];
  const float* W1      = (const float*)d_in[3];
  const float* Wc      = (const float*)d_in[4];
  const float* Wt      = (const float*)d_in[5];
  const float* b1      = (const float*)d_in[6];
  const float* W2      = (const float*)d_in[7];
  const float* b2      = (const float*)d_in[8];
  const int*   ts      = (const int*)d_in[9];
  float* out = (float*)d_out;

  char* w = (char*)d_ws;
  float*    sacp   = (float*)(w + OFF_SACP);
  float*    s1m    = (float*)(w + OFF_S1M);
  unsigned* keys   = (unsigned*)(w + OFF_KEYS);
  unsigned* cntg   = (unsigned*)(w + OFF_CNTG);
  unsigned* cntb   = (unsigned*)(w + OFF_CNTB);
  unsigned short* list = (unsigned short*)(w + OFF_LIST);
  uint4*    Bpack  = (uint4*)(w + OFF_BPACK);
  float*    noisef = (float*)(w + OFF_NOISE);
  float*    noisyf = (float*)(w + OFF_NOISY);
  float*    biasb  = (float*)(w + OFF_BIAS);
  float4*   PA     = (float4*)(w + OFF_PA);
  float4*   PB     = (float4*)(w + OFF_PB);
  float*    PC     = (float*)(w + OFF_PC);
  float*    part   = (float*)(w + OFF_PART);

  k_init<<<1, 256, 0, stream>>>(sacp, s1m, keys, cntg, cntb);
  k_biaspack<<<257, 256, 0, stream>>>(context, Wc, Wt, b1, ts, biasb,
                                      W1, W2, PA, PB, PC);
  k_prep<<<512, 256, 0, stream>>>(data, noise0, ts, sacp, s1m, Bpack, noisef, noisyf);
  for (int k = 0; k < ITERS; ++k) {
    k_argmin<<<512, 256, 0, stream>>>(k, data, ts, sacp, s1m, keys, cntg, cntb,
                                      list, Bpack, noisef, noisyf);
  }
  k_fupd<<<512, 256, 0, stream>>>(data, ts, sacp, s1m, keys, cntg, cntb, list,
                                  noisef, noisyf);
  k_loss<<<512, 256, 0, stream>>>(data, noisef, noisyf, biasb, PA, PB, PC, b2, part);
  k_red<<<1, 128, 0, stream>>>(part, out);
}